// Round 7
// baseline (35.854 us; speedup 1.0000x reference)
//
#include <hip/hip_runtime.h>
#include <hip/hip_bf16.h>
#include <math.h>

// Problem constants (DeepFM)
#define BTOT   16384
#define NF     26
#define VOCAB  100000
#define EDIM   16
#define DD     13
#define KPAD   448      // 429 padded to 14*32
#define KREAL  429
#define N1     256
#define N2     128
#define SPB    32       // samples per block (2 chunks of 16)
#define APAD   456      // A tile row stride (448+8)
#define H2PAD  264      // H2 tile row stride (256+8)

typedef __attribute__((ext_vector_type(8))) short bf16x8;
typedef __attribute__((ext_vector_type(4))) short bf16x4;
typedef __attribute__((ext_vector_type(4))) float f32x4;

static __device__ __forceinline__ bf16x8 ldb8(const __hip_bfloat16* p) {
  return *reinterpret_cast<const bf16x8*>(p);
}
static __device__ __forceinline__ short f2bf(float f) {
  __hip_bfloat16 h = __float2bfloat16(f);
  return *reinterpret_cast<short*>(&h);
}

// ---------------------------------------------------------------------------
// Kernel 1: repack weights -> bf16 B-fragment layout, coalesced reads.
//   W1  [256][429] f32 -> W1f[((k>>3)*256 + n)*8 + (k&7)]  (k padded to 448)
//   W2  [128][256] f32 -> W2f[((k>>3)*128 + n)*8 + (k&7)]
// ---------------------------------------------------------------------------
__global__ __launch_bounds__(512) void convert_weights(
    const float* __restrict__ W1, const float* __restrict__ W2,
    __hip_bfloat16* __restrict__ W1f, __hip_bfloat16* __restrict__ W2f) {
  const int bid = blockIdx.x;
  const int k = threadIdx.x;
  if (bid < 256) {
    const int n = bid;
    if (k < 448) {
      float v = (k < KREAL) ? W1[(size_t)n * KREAL + k] : 0.f;
      W1f[(((size_t)(k >> 3)) * N1 + n) * 8 + (k & 7)] = __float2bfloat16(v);
    }
  } else {
    const int n = bid - 256;
    if (k < 256) {
      float v = W2[(size_t)n * 256 + k];
      W2f[(((size_t)(k >> 3)) * N2 + n) * 8 + (k & 7)] = __float2bfloat16(v);
    }
  }
}

// ===========================================================================
// Fused kernel with wave-specialized pipeline. 512 thr = 8 waves, SPB=32,
// grid 512 (2 blocks/CU). Chunks c0 = rows 0..15, c1 = rows 16..31.
//   s0: all waves: gather+FM c0
//   s1: waves0-3 gather+FM c1 || waves4-7 GEMM1(c0)
//   s2: waves0-3 GEMM1(c1)   || waves4-7 GEMM2(c0)
//   s3: all waves GEMM2(c1); combine+sigmoid
// Separate waves => separate vmcnt streams: GEMM B-load waits are not
// poisoned by in-flight random gathers.
// ===========================================================================

__device__ __forceinline__ void gemm1_chunk(
    int r0, int w4, int lane,
    const __hip_bfloat16 (*Ash)[APAD], __hip_bfloat16 (*H2sh)[H2PAD],
    const __hip_bfloat16* __restrict__ W1f, const float* __restrict__ b1) {
  const int lr = lane & 15;
  const int kg = lane >> 4;
  const int n0 = w4 * 64;                 // 4 waves x 64 cols = 256
  f32x4 acc[4];
#pragma unroll
  for (int nt = 0; nt < 4; ++nt) acc[nt] = (f32x4){0.f, 0.f, 0.f, 0.f};

#pragma unroll
  for (int kt = 0; kt < KPAD / 32; ++kt) {
    const int kbase = kt * 32 + kg * 8;
    bf16x8 af = *reinterpret_cast<const bf16x8*>(&Ash[r0 + lr][kbase]);
#pragma unroll
    for (int nt = 0; nt < 4; ++nt) {
      bf16x8 bf = ldb8(W1f + ((size_t)(kbase >> 3) * N1 + n0 + nt * 16 + lr) * 8);
      acc[nt] = __builtin_amdgcn_mfma_f32_16x16x32_bf16(af, bf, acc[nt], 0, 0, 0);
    }
  }
#pragma unroll
  for (int nt = 0; nt < 4; ++nt) {
    const int col = n0 + nt * 16 + lr;
    const float bias = b1[col];
#pragma unroll
    for (int r = 0; r < 4; ++r) {
      float v = acc[nt][r] + bias;
      v = v > 0.f ? v : 0.f;
      H2sh[r0 + kg * 4 + r][col] = __float2bfloat16(v);
    }
  }
}

// GEMM2 over 16 rows starting at r0; `nwaves` waves participate, wave-local
// index wl in [0,nwaves); each wave covers 128/nwaves cols.
template <int NWAVES>
__device__ __forceinline__ void gemm2_chunk(
    int r0, int wl, int lane,
    const __hip_bfloat16 (*H2sh)[H2PAD], float (*redsh)[8],
    const __hip_bfloat16* __restrict__ W2f, const float* __restrict__ b2,
    const float* __restrict__ Wout) {
  const int lr = lane & 15;
  const int kg = lane >> 4;
  constexpr int NT = 128 / (16 * NWAVES);   // n-tiles per wave
  const int n0 = wl * NT * 16;
  f32x4 acc[NT];
#pragma unroll
  for (int nt = 0; nt < NT; ++nt) acc[nt] = (f32x4){0.f, 0.f, 0.f, 0.f};

#pragma unroll
  for (int kt = 0; kt < N1 / 32; ++kt) {
    const int kbase = kt * 32 + kg * 8;
    bf16x8 af = *reinterpret_cast<const bf16x8*>(&H2sh[r0 + lr][kbase]);
#pragma unroll
    for (int nt = 0; nt < NT; ++nt) {
      bf16x8 bf = ldb8(W2f + ((size_t)(kbase >> 3) * N2 + n0 + nt * 16 + lr) * 8);
      acc[nt] = __builtin_amdgcn_mfma_f32_16x16x32_bf16(af, bf, acc[nt], 0, 0, 0);
    }
  }
#pragma unroll
  for (int r = 0; r < 4; ++r) {
    float v = 0.f;
#pragma unroll
    for (int nt = 0; nt < NT; ++nt) {
      const int col = n0 + nt * 16 + lr;
      float t = acc[nt][r] + b2[col];
      t = t > 0.f ? t : 0.f;
      v += t * Wout[col];
    }
#pragma unroll
    for (int off = 1; off < 16; off <<= 1)
      v += __shfl_xor(v, off);
    if (lr == 0) redsh[r0 + kg * 4 + r][wl] = v;
  }
}

__global__ __launch_bounds__(512, 4) void deepfm_fused(
    const int* __restrict__ Xs, const float* __restrict__ Xd,
    const float* __restrict__ linW, const float* __restrict__ fmW,
    const float* __restrict__ denseW, const float* __restrict__ denseB,
    const __hip_bfloat16* __restrict__ W1f, const float* __restrict__ b1,
    const __hip_bfloat16* __restrict__ W2f, const float* __restrict__ b2,
    const float* __restrict__ Wout, float* __restrict__ out) {

  __shared__ __hip_bfloat16 Ash[SPB][APAD];
  __shared__ __hip_bfloat16 H2sh[SPB][H2PAD];
  __shared__ float fmlsh[SPB];
  __shared__ float redsh[SPB][8];

  const int tid = threadIdx.x;
  const int wave = tid >> 6;
  const int lane = tid & 63;
  const size_t blk0 = (size_t)blockIdx.x * SPB;

  // ---------------- s0: gather + FM, chunk0 (rows 0..15), all waves -------
  {
    const int s   = tid >> 5;        // 0..15
    const int sub = tid & 31;
    const int q   = sub & 3;
    const int g   = sub >> 2;        // 0..7, fields g+8i
    const size_t b = blk0 + s;
    const int* xrow = Xs + b * NF;

    int idxs[4];
#pragma unroll
    for (int i = 0; i < 4; ++i) {
      int f = g + 8 * i;
      idxs[i] = (f < NF) ? xrow[f] : 0;
    }
    f32x4 sum = (f32x4){0.f, 0.f, 0.f, 0.f};
    f32x4 sumsq = (f32x4){0.f, 0.f, 0.f, 0.f};
    float part = 0.f;
#pragma unroll
    for (int i = 0; i < 4; ++i) {
      const int f = g + 8 * i;
      if (f < NF) {
        const float* row = fmW + ((size_t)f * VOCAB + idxs[i]) * EDIM;
        f32x4 v = *reinterpret_cast<const f32x4*>(row + q * 4);
        sum += v; sumsq += v * v;
        bf16x4 pk;
        pk[0] = f2bf(v[0]); pk[1] = f2bf(v[1]);
        pk[2] = f2bf(v[2]); pk[3] = f2bf(v[3]);
        *reinterpret_cast<bf16x4*>(&Ash[s][f * EDIM + q * 4]) = pk;
        if (q == i)                   // one lin gather per (g,i)
          part += linW[(size_t)f * VOCAB + idxs[i]];
      }
    }
#pragma unroll
    for (int off = 4; off <= 16; off <<= 1) {
#pragma unroll
      for (int c = 0; c < 4; ++c) {
        sum[c] += __shfl_xor(sum[c], off);
        sumsq[c] += __shfl_xor(sumsq[c], off);
      }
    }
    if (g == 0) {
      f32x4 c4 = sum * sum - sumsq;
      part += 0.5f * (c4[0] + c4[1] + c4[2] + c4[3]);
    }
    float xd = (sub < DD) ? Xd[b * DD + sub] : 0.f;
    Ash[s][416 + sub] = __float2bfloat16(xd);
    if (sub < DD) part += xd * denseW[sub];
#pragma unroll
    for (int off = 1; off < 32; off <<= 1)
      part += __shfl_xor(part, off);
    if (sub == 0) fmlsh[s] = part + denseB[0];
  }
  __syncthreads();

  // ---------------- s1: waves0-3 gather c1 || waves4-7 GEMM1(c0) ----------
  if (wave < 4) {
    const int t   = tid;             // 0..255
    const int s   = 16 + (t >> 4);   // rows 16..31
    const int sub = t & 15;
    const int q   = sub & 3;
    const int g   = sub >> 2;        // 0..3, fields g+4i
    const size_t b = blk0 + s;
    const int* xrow = Xs + b * NF;

    int idxs[7];
#pragma unroll
    for (int i = 0; i < 7; ++i) {
      int f = g + 4 * i;
      idxs[i] = (f < NF) ? xrow[f] : 0;
    }
    f32x4 sum = (f32x4){0.f, 0.f, 0.f, 0.f};
    f32x4 sumsq = (f32x4){0.f, 0.f, 0.f, 0.f};
    float part = 0.f;
#pragma unroll
    for (int i = 0; i < 7; ++i) {
      const int f = g + 4 * i;
      if (f < NF) {
        const float* row = fmW + ((size_t)f * VOCAB + idxs[i]) * EDIM;
        f32x4 v = *reinterpret_cast<const f32x4*>(row + q * 4);
        sum += v; sumsq += v * v;
        bf16x4 pk;
        pk[0] = f2bf(v[0]); pk[1] = f2bf(v[1]);
        pk[2] = f2bf(v[2]); pk[3] = f2bf(v[3]);
        *reinterpret_cast<bf16x4*>(&Ash[s][f * EDIM + q * 4]) = pk;
        if (q == (i & 3))
          part += linW[(size_t)f * VOCAB + idxs[i]];
      }
    }
#pragma unroll
    for (int off = 4; off <= 8; off <<= 1) {
#pragma unroll
      for (int c = 0; c < 4; ++c) {
        sum[c] += __shfl_xor(sum[c], off);
        sumsq[c] += __shfl_xor(sumsq[c], off);
      }
    }
    if (g == 0) {
      f32x4 c4 = sum * sum - sumsq;
      part += 0.5f * (c4[0] + c4[1] + c4[2] + c4[3]);
    }
    float xd = (sub < DD) ? Xd[b * DD + sub] : 0.f;
    Ash[s][416 + sub] = __float2bfloat16(xd);
    Ash[s][432 + sub] = __float2bfloat16(0.f);
    if (sub < DD) part += xd * denseW[sub];
#pragma unroll
    for (int off = 1; off < 16; off <<= 1)
      part += __shfl_xor(part, off);
    if (sub == 0) fmlsh[s] = part + denseB[0];
  } else {
    gemm1_chunk(0, wave - 4, lane, Ash, H2sh, W1f, b1);
  }
  __syncthreads();

  // ---------------- s2: waves0-3 GEMM1(c1) || waves4-7 GEMM2(c0) ----------
  if (wave < 4) {
    gemm1_chunk(16, wave, lane, Ash, H2sh, W1f, b1);
  } else {
    gemm2_chunk<4>(0, wave - 4, lane, H2sh, redsh, W2f, b2, Wout);
  }
  __syncthreads();

  // ---------------- s3: all 8 waves GEMM2(c1) -----------------------------
  gemm2_chunk<8>(16, wave, lane, H2sh, redsh, W2f, b2, Wout);
  __syncthreads();

  // ---------------- combine + sigmoid -------------------------------------
  if (tid < SPB) {
    const int row = tid;
    const int nslots = (row < 16) ? 4 : 8;
    float t = 0.f;
    for (int w = 0; w < nslots; ++w) t += redsh[row][w];
    float x = fmlsh[row] + t;
    out[blk0 + row] = 1.f / (1.f + expf(-x));
  }
}

// ---------------------------------------------------------------------------
extern "C" void kernel_launch(void* const* d_in, const int* in_sizes, int n_in,
                              void* d_out, int out_size, void* d_ws, size_t ws_size,
                              hipStream_t stream) {
  const int*   Xs   = (const int*)d_in[0];
  const float* Xd   = (const float*)d_in[1];
  const float* linW = (const float*)d_in[2];
  const float* fmW  = (const float*)d_in[3];
  const float* dW   = (const float*)d_in[4];
  const float* dB   = (const float*)d_in[5];
  const float* W1   = (const float*)d_in[6];
  const float* b1   = (const float*)d_in[7];
  const float* W2   = (const float*)d_in[8];
  const float* b2   = (const float*)d_in[9];
  const float* Wout = (const float*)d_in[10];
  float* out = (float*)d_out;

  char* ws = (char*)d_ws;
  __hip_bfloat16* W1f = (__hip_bfloat16*)(ws);             // 448*256*2 = 229,376
  __hip_bfloat16* W2f = (__hip_bfloat16*)(ws + 229376);    // 256*128*2 =  65,536

  convert_weights<<<384, 512, 0, stream>>>(W1, W2, W1f, W2f);
  deepfm_fused<<<BTOT / SPB, 512, 0, stream>>>(
      Xs, Xd, linW, fmW, dW, dB, W1f, b1, W2f, b2, Wout, out);
}